// Round 1
// baseline (2638.138 us; speedup 1.0000x reference)
//
#include <hip/hip_runtime.h>

#define NN 100000
#define NE 1200000

// ---------------- degree / norm precompute ----------------
__global__ void k_degree(const int* __restrict__ ei, float* __restrict__ deg) {
    int i = blockIdx.x * 256 + threadIdx.x;
    if (i < NE) atomicAdd(&deg[ei[NE + i]], 1.0f);   // dst row of edge_index
}

__global__ void k_dinv(const float* __restrict__ deg, float* __restrict__ dinv) {
    int i = blockIdx.x * 256 + threadIdx.x;
    if (i < NN) dinv[i] = rsqrtf(deg[i] + 1.0f);
}

__global__ void k_norm(const int* __restrict__ ei, const float* __restrict__ dinv,
                       float* __restrict__ nrm) {
    int e = blockIdx.x * 256 + threadIdx.x;
    if (e < NE) nrm[e] = dinv[ei[e]] * dinv[ei[NE + e]];
}

// ---------------- matmuls (write h AND agg_init = h*dinv^2) ----------------
__global__ void k_lin_first(const float* __restrict__ x, const float* __restrict__ W,
                            const float* __restrict__ dinv,
                            float* __restrict__ h, float* __restrict__ agg) {
    __shared__ float Ws[5 * 64];
    int t = threadIdx.x;
    for (int i = t; i < 320; i += 256) Ws[i] = W[i];
    __syncthreads();
    int r = t >> 6, c = t & 63;
    int row = blockIdx.x * 4 + r;
    if (row >= NN) return;
    float acc = 0.f;
#pragma unroll
    for (int k = 0; k < 5; k++) acc += x[row * 5 + k] * Ws[k * 64 + c];
    float dv = dinv[row];
    h[row * 64 + c] = acc;
    agg[row * 64 + c] = acc * dv * dv;
}

// 64->64, safe for agg==in (rows staged to LDS, barrier, then write own rows)
__global__ void k_lin64(const float* __restrict__ in, const float* __restrict__ W,
                        const float* __restrict__ dinv,
                        float* __restrict__ h, float* __restrict__ agg) {
    __shared__ float Ws[64 * 64];
    __shared__ float rows[256];
    int t = threadIdx.x;
    for (int i = t; i < 4096; i += 256) Ws[i] = W[i];
    int base = blockIdx.x * 4;
    int gidx = base * 64 + t;
    rows[t] = (gidx < NN * 64) ? in[gidx] : 0.f;
    __syncthreads();
    int r = t >> 6, c = t & 63, row = base + r;
    if (row >= NN) return;
    float acc = 0.f;
#pragma unroll
    for (int k = 0; k < 64; k++) acc += rows[r * 64 + k] * Ws[k * 64 + c];
    float dv = dinv[row];
    h[row * 64 + c] = acc;
    agg[row * 64 + c] = acc * dv * dv;
}

// 64->16
__global__ void k_lin3(const float* __restrict__ in, const float* __restrict__ W,
                       const float* __restrict__ dinv,
                       float* __restrict__ h, float* __restrict__ agg) {
    __shared__ float Ws[64 * 16];
    __shared__ float rows[16 * 64];
    int t = threadIdx.x;
    for (int i = t; i < 1024; i += 256) Ws[i] = W[i];
    int base = blockIdx.x * 16;
    for (int i = t; i < 1024; i += 256) {
        int g = base * 64 + i;
        rows[i] = (g < NN * 64) ? in[g] : 0.f;
    }
    __syncthreads();
    int r = t >> 4, c = t & 15, row = base + r;
    if (row >= NN) return;
    float acc = 0.f;
#pragma unroll
    for (int k = 0; k < 64; k++) acc += rows[r * 64 + k] * Ws[k * 16 + c];
    float dv = dinv[row];
    h[row * 16 + c] = acc;
    agg[row * 16 + c] = acc * dv * dv;
}

// ---------------- edge aggregation: agg[dst] += h[src] * norm[e] ----------------
template <int F>
__global__ void k_edge(const int* __restrict__ ei, const float* __restrict__ nrm,
                       const float* __restrict__ h, float* __restrict__ agg) {
    constexpr int C = F / 4;                 // float4 chunks per edge
    int idx = blockIdx.x * 256 + threadIdx.x;
    if (idx >= NE * C) return;
    int e = idx / C;
    int c = idx % C;
    int src = ei[e];
    int dst = ei[NE + e];
    float w = nrm[e];
    float4 v = reinterpret_cast<const float4*>(h)[src * C + c];
    float* ap = agg + (size_t)dst * F + c * 4;
    atomicAdd(ap + 0, v.x * w);
    atomicAdd(ap + 1, v.y * w);
    atomicAdd(ap + 2, v.z * w);
    atomicAdd(ap + 3, v.w * w);
}

// ---------------- bias (+relu) in place ----------------
template <int F, bool RELU>
__global__ void k_bias(float* __restrict__ a, const float* __restrict__ b) {
    int idx = blockIdx.x * 256 + threadIdx.x;
    if (idx >= NN * F) return;
    int j = idx % F;
    float v = a[idx] + b[j];
    if (RELU) v = fmaxf(v, 0.f);
    a[idx] = v;
}

// ---------------- reductions ----------------
__global__ void k_reduce_emb(const float* __restrict__ a, float* __restrict__ red) {
    __shared__ float s[256];
    int t = threadIdx.x, c = t & 15;
    float sum = 0.f;
    for (int r = blockIdx.x * 16 + (t >> 4); r < NN; r += gridDim.x * 16)
        sum += a[r * 16 + c];
    s[t] = sum;
    __syncthreads();
    for (int off = 128; off >= 16; off >>= 1) {
        if (t < off) s[t] += s[t + off];
        __syncthreads();
    }
    if (t < 16) atomicAdd(&red[t], s[t]);
}

__global__ void k_reduce_gf(const float* __restrict__ x, float* __restrict__ red) {
    int t = threadIdx.x;
    float sc = 0, sa = 0, so = 0, sl = 0, sm = 0;
    for (int i = blockIdx.x * 256 + t; i < NN; i += gridDim.x * 256) {
        float lam = x[i * 5 + 0], mu = x[i * 5 + 1];
        float c = x[i * 5 + 2], a = x[i * 5 + 3], o = x[i * 5 + 4];
        sc += c; sa += a; so += o; sl += lam * c; sm += mu * c;
    }
    __shared__ float s[256];
    float vals[5] = {sc, sa, so, sl, sm};
#pragma unroll
    for (int k = 0; k < 5; k++) {
        s[t] = vals[k];
        __syncthreads();
        for (int off = 128; off > 0; off >>= 1) {
            if (t < off) s[t] += s[t + off];
            __syncthreads();
        }
        if (t == 0) atomicAdd(&red[16 + k], s[0]);
        __syncthreads();
    }
}

// ---------------- final MLP (1 block, 64 threads) ----------------
__device__ __forceinline__ float softplus_f(float x) {
    return (x > 20.f) ? x : log1pf(expf(x));
}

__global__ void k_mlp(const float* __restrict__ red,
                      const float* __restrict__ T, const float* __restrict__ Tmax,
                      const float* __restrict__ P1, const float* __restrict__ pb1,
                      const float* __restrict__ P2, const float* __restrict__ pb2,
                      const float* __restrict__ P3, const float* __restrict__ pb3,
                      float* __restrict__ out) {
    __shared__ float emb[24];
    __shared__ float hm1[64];
    __shared__ float hm2[32];
    __shared__ float val[4];
    int t = threadIdx.x;
    if (t < 16) emb[t] = red[t] / (float)NN;
    if (t == 0) {
        float sc = red[16], sa = red[17], so = red[18], sl = red[19], sm = red[20];
        float Tn = T[0] / Tmax[0];
        emb[16] = sc;
        emb[17] = sa;
        emb[18] = so;
        emb[19] = sa + so;
        float safe = fmaxf(sc, 1.0f);
        bool has = sc > 0.f;
        emb[20] = has ? sl / safe : 0.f;
        emb[21] = has ? sm / safe : 0.f;
        emb[22] = Tn * 50.f;
        emb[23] = (1.f / (1.f + Tn)) * 50.f;
    }
    __syncthreads();
    // P1: (24,64)
    {
        float acc = pb1[t];
#pragma unroll
        for (int k = 0; k < 24; k++) acc += emb[k] * P1[k * 64 + t];
        hm1[t] = fmaxf(acc, 0.f);
    }
    __syncthreads();
    if (t < 32) {
        float acc = pb2[t];
#pragma unroll
        for (int k = 0; k < 64; k++) acc += hm1[k] * P2[k * 32 + t];
        hm2[t] = fmaxf(acc, 0.f);
    }
    __syncthreads();
    if (t < 4) {
        float acc = pb3[t];
#pragma unroll
        for (int k = 0; k < 32; k++) acc += hm2[k] * P3[k * 4 + t];
        val[t] = softplus_f(acc + 2.0f);
    }
    __syncthreads();
    if (t == 0) {
        float amin = 1.f + val[0];
        float amax = amin + val[1] + 0.5f;
        float bmin = 1.f + val[2];
        float bmax = bmin + val[3] + 0.5f;
        out[0] = amin; out[1] = amax; out[2] = bmin; out[3] = bmax;
    }
    if (t >= 4 && t < 28) out[t] = emb[t - 4];
}

extern "C" void kernel_launch(void* const* d_in, const int* in_sizes, int n_in,
                              void* d_out, int out_size, void* d_ws, size_t ws_size,
                              hipStream_t stream) {
    const float* x    = (const float*)d_in[0];
    const int*   ei   = (const int*)d_in[1];
    const float* T    = (const float*)d_in[2];
    const float* Tmax = (const float*)d_in[3];
    const float* W1   = (const float*)d_in[4];
    const float* b1   = (const float*)d_in[5];
    const float* W2   = (const float*)d_in[6];
    const float* b2   = (const float*)d_in[7];
    const float* W3   = (const float*)d_in[8];
    const float* b3   = (const float*)d_in[9];
    const float* P1   = (const float*)d_in[10];
    const float* pb1  = (const float*)d_in[11];
    const float* P2   = (const float*)d_in[12];
    const float* pb2  = (const float*)d_in[13];
    const float* P3   = (const float*)d_in[14];
    const float* pb3  = (const float*)d_in[15];
    float* out = (float*)d_out;

    float* ws   = (float*)d_ws;
    float* bufH = ws;                       // N*64
    float* bufA = bufH + (size_t)NN * 64;   // N*64
    float* dinv = bufA + (size_t)NN * 64;   // N
    float* deg  = dinv + NN;                // N
    float* nrm  = deg + NN;                 // E
    float* red  = nrm + NE;                 // 32

    float* h3   = bufH;                     // N*16
    float* agg3 = bufH + (size_t)NN * 16;   // N*16

    hipMemsetAsync(deg, 0, NN * sizeof(float), stream);
    hipMemsetAsync(red, 0, 32 * sizeof(float), stream);

    k_degree<<<(NE + 255) / 256, 256, 0, stream>>>(ei, deg);
    k_dinv<<<(NN + 255) / 256, 256, 0, stream>>>(deg, dinv);
    k_norm<<<(NE + 255) / 256, 256, 0, stream>>>(ei, dinv, nrm);

    // layer 1: x(N,5) @ W1 -> relu(gcn)
    k_lin_first<<<(NN + 3) / 4, 256, 0, stream>>>(x, W1, dinv, bufH, bufA);
    k_edge<64><<<(NE * 16 + 255) / 256, 256, 0, stream>>>(ei, nrm, bufH, bufA);
    k_bias<64, true><<<(NN * 64 + 255) / 256, 256, 0, stream>>>(bufA, b1);

    // layer 2: bufA @ W2 -> relu(gcn)
    k_lin64<<<(NN + 3) / 4, 256, 0, stream>>>(bufA, W2, dinv, bufH, bufA);
    k_edge<64><<<(NE * 16 + 255) / 256, 256, 0, stream>>>(ei, nrm, bufH, bufA);
    k_bias<64, true><<<(NN * 64 + 255) / 256, 256, 0, stream>>>(bufA, b2);

    // layer 3: bufA @ W3 -> gcn (no relu)
    k_lin3<<<(NN + 15) / 16, 256, 0, stream>>>(bufA, W3, dinv, h3, agg3);
    k_edge<16><<<(NE * 4 + 255) / 256, 256, 0, stream>>>(ei, nrm, h3, agg3);
    k_bias<16, false><<<(NN * 16 + 255) / 256, 256, 0, stream>>>(agg3, b3);

    // reductions + MLP
    k_reduce_emb<<<1024, 256, 0, stream>>>(agg3, red);
    k_reduce_gf<<<1024, 256, 0, stream>>>(x, red);
    k_mlp<<<1, 64, 0, stream>>>(red, T, Tmax, P1, pb1, P2, pb2, P3, pb3, out);
}

// Round 2
// 629.291 us; speedup vs baseline: 4.1922x; 4.1922x over previous
//
#include <hip/hip_runtime.h>

#define NN 100000
#define NE 1200000
#define NB_SCAN ((NN + 255) / 256)   // 391 blocks

// ---------------- CSR build ----------------
__global__ void k_hist(const int* __restrict__ ei, int* __restrict__ cnt) {
    int i = blockIdx.x * 256 + threadIdx.x;
    if (i < NE) atomicAdd(&cnt[ei[NE + i]], 1);   // dst row
}

__global__ void k_dinv(const int* __restrict__ cnt, float* __restrict__ dinv) {
    int i = blockIdx.x * 256 + threadIdx.x;
    if (i < NN) dinv[i] = rsqrtf((float)cnt[i] + 1.0f);
}

__global__ void k_scan_block(const int* __restrict__ cnt, int* __restrict__ incl,
                             int* __restrict__ bsum) {
    __shared__ int s[256];
    int t = threadIdx.x;
    int i = blockIdx.x * 256 + t;
    s[t] = (i < NN) ? cnt[i] : 0;
    __syncthreads();
    for (int off = 1; off < 256; off <<= 1) {
        int add = (t >= off) ? s[t - off] : 0;
        __syncthreads();
        s[t] += add;
        __syncthreads();
    }
    if (i < NN) incl[i] = s[t];
    if (t == 255) bsum[blockIdx.x] = s[255];
}

__global__ void k_scan_bsum(int* __restrict__ bsum) {
    __shared__ int s[512];
    int t = threadIdx.x;
    s[t] = (t < NB_SCAN) ? bsum[t] : 0;
    __syncthreads();
    for (int off = 1; off < 512; off <<= 1) {
        int add = (t >= off) ? s[t - off] : 0;
        __syncthreads();
        s[t] += add;
        __syncthreads();
    }
    if (t < NB_SCAN) bsum[t] = s[t];
}

__global__ void k_scan_add(const int* __restrict__ cnt, const int* __restrict__ incl,
                           const int* __restrict__ bsum, int* __restrict__ rowptr) {
    int i = blockIdx.x * 256 + threadIdx.x;
    if (i >= NN) return;
    int base = (blockIdx.x > 0) ? bsum[blockIdx.x - 1] : 0;
    rowptr[i] = base + incl[i] - cnt[i];   // exclusive scan
    if (i == 0) rowptr[NN] = NE;
}

__global__ void k_scatter(const int* __restrict__ ei, const int* __restrict__ rowptr,
                          int* __restrict__ cursor, int* __restrict__ srcs) {
    int e = blockIdx.x * 256 + threadIdx.x;
    if (e >= NE) return;
    int dst = ei[NE + e];
    int pos = rowptr[dst] + atomicAdd(&cursor[dst], 1);
    srcs[pos] = ei[e];
}

// ---------------- matmuls (write h only) ----------------
__global__ void k_lin_first(const float* __restrict__ x, const float* __restrict__ W,
                            float* __restrict__ h) {
    __shared__ float Ws[5 * 64];
    int t = threadIdx.x;
    for (int i = t; i < 320; i += 256) Ws[i] = W[i];
    __syncthreads();
    int r = t >> 6, c = t & 63;
    int row = blockIdx.x * 4 + r;
    if (row >= NN) return;
    float acc = 0.f;
#pragma unroll
    for (int k = 0; k < 5; k++) acc += x[row * 5 + k] * Ws[k * 64 + c];
    h[(size_t)row * 64 + c] = acc;
}

__global__ void k_lin64(const float* __restrict__ in, const float* __restrict__ W,
                        float* __restrict__ h) {
    __shared__ float Ws[64 * 64];
    __shared__ float rows[256];
    int t = threadIdx.x;
    for (int i = t; i < 4096; i += 256) Ws[i] = W[i];
    int base = blockIdx.x * 4;
    int gidx = base * 64 + t;
    rows[t] = (gidx < NN * 64) ? in[gidx] : 0.f;
    __syncthreads();
    int r = t >> 6, c = t & 63, row = base + r;
    if (row >= NN) return;
    float acc = 0.f;
#pragma unroll
    for (int k = 0; k < 64; k++) acc += rows[r * 64 + k] * Ws[k * 64 + c];
    h[(size_t)row * 64 + c] = acc;
}

__global__ void k_lin3(const float* __restrict__ in, const float* __restrict__ W,
                       float* __restrict__ h) {
    __shared__ float Ws[64 * 16];
    __shared__ float rows[16 * 64];
    int t = threadIdx.x;
    for (int i = t; i < 1024; i += 256) Ws[i] = W[i];
    int base = blockIdx.x * 16;
    for (int i = t; i < 1024; i += 256) {
        int g = base * 64 + i;
        rows[i] = (g < NN * 64) ? in[g] : 0.f;
    }
    __syncthreads();
    int r = t >> 4, c = t & 15, row = base + r;
    if (row >= NN) return;
    float acc = 0.f;
#pragma unroll
    for (int k = 0; k < 64; k++) acc += rows[r * 64 + k] * Ws[k * 16 + c];
    h[(size_t)row * 16 + c] = acc;
}

// ---------------- pull aggregation: out[n] = sum_{e:dst=n} h[src]*w + self + bias ----------------
template <bool RELU>
__global__ void k_agg64(const int* __restrict__ rowptr, const int* __restrict__ srcs,
                        const float* __restrict__ dinv, const float* __restrict__ h,
                        const float* __restrict__ b, float* __restrict__ out) {
    int t = threadIdx.x;
    int n = blockIdx.x * 4 + (t >> 6);
    if (n >= NN) return;
    int c = t & 63;
    int e0 = rowptr[n], e1 = rowptr[n + 1];
    float dvn = dinv[n];
    float acc0 = 0.f, acc1 = 0.f;
    int j = e0;
    for (; j + 1 < e1; j += 2) {
        int s0 = srcs[j], s1 = srcs[j + 1];
        float w0 = dinv[s0] * dvn, w1 = dinv[s1] * dvn;
        acc0 += h[(size_t)s0 * 64 + c] * w0;
        acc1 += h[(size_t)s1 * 64 + c] * w1;
    }
    if (j < e1) {
        int s0 = srcs[j];
        acc0 += h[(size_t)s0 * 64 + c] * (dinv[s0] * dvn);
    }
    float v = acc0 + acc1 + h[(size_t)n * 64 + c] * dvn * dvn + b[c];
    if (RELU) v = fmaxf(v, 0.f);
    out[(size_t)n * 64 + c] = v;
}

// layer-3 aggregation fused with emb-mean reduction (agg3 never materialized)
__global__ void k_agg16_reduce(const int* __restrict__ rowptr, const int* __restrict__ srcs,
                               const float* __restrict__ dinv, const float* __restrict__ h,
                               const float* __restrict__ b, float* __restrict__ red) {
    __shared__ float s[256];
    int t = threadIdx.x;
    int c = t & 15;
    int n = blockIdx.x * 16 + (t >> 4);
    float v = 0.f;
    if (n < NN) {
        int e0 = rowptr[n], e1 = rowptr[n + 1];
        float dvn = dinv[n];
        float acc = 0.f;
        for (int j = e0; j < e1; j++) {
            int s0 = srcs[j];
            acc += h[(size_t)s0 * 16 + c] * (dinv[s0] * dvn);
        }
        v = acc + h[(size_t)n * 16 + c] * dvn * dvn + b[c];
    }
    s[t] = v;
    __syncthreads();
    for (int off = 128; off >= 16; off >>= 1) {
        if (t < off) s[t] += s[t + off];
        __syncthreads();
    }
    if (t < 16) atomicAdd(&red[t], s[t]);
}

// ---------------- global-feature reduction ----------------
__global__ void k_reduce_gf(const float* __restrict__ x, float* __restrict__ red) {
    int t = threadIdx.x;
    float sc = 0, sa = 0, so = 0, sl = 0, sm = 0;
    for (int i = blockIdx.x * 256 + t; i < NN; i += gridDim.x * 256) {
        float lam = x[i * 5 + 0], mu = x[i * 5 + 1];
        float c = x[i * 5 + 2], a = x[i * 5 + 3], o = x[i * 5 + 4];
        sc += c; sa += a; so += o; sl += lam * c; sm += mu * c;
    }
    __shared__ float s[256];
    float vals[5] = {sc, sa, so, sl, sm};
#pragma unroll
    for (int k = 0; k < 5; k++) {
        s[t] = vals[k];
        __syncthreads();
        for (int off = 128; off > 0; off >>= 1) {
            if (t < off) s[t] += s[t + off];
            __syncthreads();
        }
        if (t == 0) atomicAdd(&red[16 + k], s[0]);
        __syncthreads();
    }
}

// ---------------- final MLP (1 block, 64 threads) ----------------
__device__ __forceinline__ float softplus_f(float x) {
    return (x > 20.f) ? x : log1pf(expf(x));
}

__global__ void k_mlp(const float* __restrict__ red,
                      const float* __restrict__ T, const float* __restrict__ Tmax,
                      const float* __restrict__ P1, const float* __restrict__ pb1,
                      const float* __restrict__ P2, const float* __restrict__ pb2,
                      const float* __restrict__ P3, const float* __restrict__ pb3,
                      float* __restrict__ out) {
    __shared__ float emb[24];
    __shared__ float hm1[64];
    __shared__ float hm2[32];
    __shared__ float val[4];
    int t = threadIdx.x;
    if (t < 16) emb[t] = red[t] / (float)NN;   // b3 already folded per-node
    if (t == 0) {
        float sc = red[16], sa = red[17], so = red[18], sl = red[19], sm = red[20];
        float Tn = T[0] / Tmax[0];
        emb[16] = sc;
        emb[17] = sa;
        emb[18] = so;
        emb[19] = sa + so;
        float safe = fmaxf(sc, 1.0f);
        bool has = sc > 0.f;
        emb[20] = has ? sl / safe : 0.f;
        emb[21] = has ? sm / safe : 0.f;
        emb[22] = Tn * 50.f;
        emb[23] = (1.f / (1.f + Tn)) * 50.f;
    }
    __syncthreads();
    {
        float acc = pb1[t];
#pragma unroll
        for (int k = 0; k < 24; k++) acc += emb[k] * P1[k * 64 + t];
        hm1[t] = fmaxf(acc, 0.f);
    }
    __syncthreads();
    if (t < 32) {
        float acc = pb2[t];
#pragma unroll
        for (int k = 0; k < 64; k++) acc += hm1[k] * P2[k * 32 + t];
        hm2[t] = fmaxf(acc, 0.f);
    }
    __syncthreads();
    if (t < 4) {
        float acc = pb3[t];
#pragma unroll
        for (int k = 0; k < 32; k++) acc += hm2[k] * P3[k * 4 + t];
        val[t] = softplus_f(acc + 2.0f);
    }
    __syncthreads();
    if (t == 0) {
        float amin = 1.f + val[0];
        float amax = amin + val[1] + 0.5f;
        float bmin = 1.f + val[2];
        float bmax = bmin + val[3] + 0.5f;
        out[0] = amin; out[1] = amax; out[2] = bmin; out[3] = bmax;
    }
    if (t >= 4 && t < 28) out[t] = emb[t - 4];
}

extern "C" void kernel_launch(void* const* d_in, const int* in_sizes, int n_in,
                              void* d_out, int out_size, void* d_ws, size_t ws_size,
                              hipStream_t stream) {
    const float* x    = (const float*)d_in[0];
    const int*   ei   = (const int*)d_in[1];
    const float* T    = (const float*)d_in[2];
    const float* Tmax = (const float*)d_in[3];
    const float* W1   = (const float*)d_in[4];
    const float* b1   = (const float*)d_in[5];
    const float* W2   = (const float*)d_in[6];
    const float* b2   = (const float*)d_in[7];
    const float* W3   = (const float*)d_in[8];
    const float* b3   = (const float*)d_in[9];
    const float* P1   = (const float*)d_in[10];
    const float* pb1  = (const float*)d_in[11];
    const float* P2   = (const float*)d_in[12];
    const float* pb2  = (const float*)d_in[13];
    const float* P3   = (const float*)d_in[14];
    const float* pb3  = (const float*)d_in[15];
    float* out = (float*)d_out;

    // workspace carve-up
    char* w = (char*)d_ws;
    float* bufH   = (float*)w;                 w += (size_t)NN * 64 * 4;   // 25.6MB
    float* bufA   = (float*)w;                 w += (size_t)NN * 64 * 4;   // 25.6MB
    float* dinv   = (float*)w;                 w += (size_t)NN * 4;
    int*   cnt    = (int*)w;                   w += (size_t)NN * 4;
    int*   incl   = (int*)w;                   w += (size_t)NN * 4;
    int*   rowptr = (int*)w;                   w += (size_t)(NN + 1) * 4;
    int*   cursor = (int*)w;                   w += (size_t)NN * 4;
    int*   srcs   = (int*)w;                   w += (size_t)NE * 4;        // 4.8MB
    int*   bsum   = (int*)w;                   w += 512 * 4;
    float* red    = (float*)w;                 w += 32 * 4;

    hipMemsetAsync(cnt, 0, NN * sizeof(int), stream);
    hipMemsetAsync(cursor, 0, NN * sizeof(int), stream);
    hipMemsetAsync(red, 0, 32 * sizeof(float), stream);

    // CSR build (by dst) + dinv
    k_hist<<<(NE + 255) / 256, 256, 0, stream>>>(ei, cnt);
    k_dinv<<<(NN + 255) / 256, 256, 0, stream>>>(cnt, dinv);
    k_scan_block<<<NB_SCAN, 256, 0, stream>>>(cnt, incl, bsum);
    k_scan_bsum<<<1, 512, 0, stream>>>(bsum);
    k_scan_add<<<NB_SCAN, 256, 0, stream>>>(cnt, incl, bsum, rowptr);
    k_scatter<<<(NE + 255) / 256, 256, 0, stream>>>(ei, rowptr, cursor, srcs);

    // layer 1
    k_lin_first<<<(NN + 3) / 4, 256, 0, stream>>>(x, W1, bufH);
    k_agg64<true><<<(NN + 3) / 4, 256, 0, stream>>>(rowptr, srcs, dinv, bufH, b1, bufA);

    // layer 2
    k_lin64<<<(NN + 3) / 4, 256, 0, stream>>>(bufA, W2, bufH);
    k_agg64<true><<<(NN + 3) / 4, 256, 0, stream>>>(rowptr, srcs, dinv, bufH, b2, bufA);

    // layer 3 (16-wide) + fused emb-mean
    k_lin3<<<(NN + 15) / 16, 256, 0, stream>>>(bufA, W3, bufH);
    k_agg16_reduce<<<(NN + 15) / 16, 256, 0, stream>>>(rowptr, srcs, dinv, bufH, b3, red);

    // global features + MLP
    k_reduce_gf<<<1024, 256, 0, stream>>>(x, red);
    k_mlp<<<1, 64, 0, stream>>>(red, T, Tmax, P1, pb1, P2, pb2, P3, pb3, out);
}

// Round 3
// 564.675 us; speedup vs baseline: 4.6720x; 1.1144x over previous
//
#include <hip/hip_runtime.h>

#define NN 100000
#define NE 1200000
#define NB_SCAN ((NN + 255) / 256)   // 391 blocks

// ---------------- CSR build ----------------
__global__ void k_hist(const int* __restrict__ ei, int* __restrict__ cnt) {
    int i = blockIdx.x * 256 + threadIdx.x;
    if (i < NE) atomicAdd(&cnt[ei[NE + i]], 1);   // dst row
}

// scan block + dinv fused (reads cnt anyway)
__global__ void k_scan_block(const int* __restrict__ cnt, int* __restrict__ incl,
                             int* __restrict__ bsum, float* __restrict__ dinv) {
    __shared__ int s[256];
    int t = threadIdx.x;
    int i = blockIdx.x * 256 + t;
    int v = (i < NN) ? cnt[i] : 0;
    if (i < NN) dinv[i] = rsqrtf((float)v + 1.0f);
    s[t] = v;
    __syncthreads();
    for (int off = 1; off < 256; off <<= 1) {
        int add = (t >= off) ? s[t - off] : 0;
        __syncthreads();
        s[t] += add;
        __syncthreads();
    }
    if (i < NN) incl[i] = s[t];
    if (t == 255) bsum[blockIdx.x] = s[255];
}

__global__ void k_scan_bsum(int* __restrict__ bsum) {
    __shared__ int s[512];
    int t = threadIdx.x;
    s[t] = (t < NB_SCAN) ? bsum[t] : 0;
    __syncthreads();
    for (int off = 1; off < 512; off <<= 1) {
        int add = (t >= off) ? s[t - off] : 0;
        __syncthreads();
        s[t] += add;
        __syncthreads();
    }
    if (t < NB_SCAN) bsum[t] = s[t];
}

__global__ void k_scan_add(const int* __restrict__ cnt, const int* __restrict__ incl,
                           const int* __restrict__ bsum, int* __restrict__ rowptr) {
    int i = blockIdx.x * 256 + threadIdx.x;
    if (i >= NN) return;
    int base = (blockIdx.x > 0) ? bsum[blockIdx.x - 1] : 0;
    rowptr[i] = base + incl[i] - cnt[i];   // exclusive scan
    if (i == 0) rowptr[NN] = NE;
}

__global__ void k_scatter(const int* __restrict__ ei, const int* __restrict__ rowptr,
                          int* __restrict__ cursor, int* __restrict__ srcs) {
    int e = blockIdx.x * 256 + threadIdx.x;
    if (e >= NE) return;
    int dst = ei[NE + e];
    int pos = rowptr[dst] + atomicAdd(&cursor[dst], 1);
    srcs[pos] = ei[e];
}

// ---------------- matmuls (write h only) ----------------
__global__ void k_lin_first(const float* __restrict__ x, const float* __restrict__ W,
                            float* __restrict__ h) {
    __shared__ float Ws[5 * 64];
    int t = threadIdx.x;
    for (int i = t; i < 320; i += 256) Ws[i] = W[i];
    __syncthreads();
    int r = t >> 6, c = t & 63;
    int row = blockIdx.x * 4 + r;
    if (row >= NN) return;
    float acc = 0.f;
#pragma unroll
    for (int k = 0; k < 5; k++) acc += x[row * 5 + k] * Ws[k * 64 + c];
    h[(size_t)row * 64 + c] = acc;
}

__global__ void k_lin64(const float* __restrict__ in, const float* __restrict__ W,
                        float* __restrict__ h) {
    __shared__ float Ws[64 * 64];
    __shared__ float rows[256];
    int t = threadIdx.x;
    for (int i = t; i < 4096; i += 256) Ws[i] = W[i];
    int base = blockIdx.x * 4;
    int gidx = base * 64 + t;
    rows[t] = (gidx < NN * 64) ? in[gidx] : 0.f;
    __syncthreads();
    int r = t >> 6, c = t & 63, row = base + r;
    if (row >= NN) return;
    float acc = 0.f;
#pragma unroll
    for (int k = 0; k < 64; k++) acc += rows[r * 64 + k] * Ws[k * 64 + c];
    h[(size_t)row * 64 + c] = acc;
}

__global__ void k_lin3(const float* __restrict__ in, const float* __restrict__ W,
                       float* __restrict__ h) {
    __shared__ float Ws[64 * 16];
    __shared__ float rows[16 * 64];
    int t = threadIdx.x;
    for (int i = t; i < 1024; i += 256) Ws[i] = W[i];
    int base = blockIdx.x * 16;
    for (int i = t; i < 1024; i += 256) {
        int g = base * 64 + i;
        rows[i] = (g < NN * 64) ? in[g] : 0.f;
    }
    __syncthreads();
    int r = t >> 4, c = t & 15, row = base + r;
    if (row >= NN) return;
    float acc = 0.f;
#pragma unroll
    for (int k = 0; k < 64; k++) acc += rows[r * 64 + k] * Ws[k * 16 + c];
    h[(size_t)row * 16 + c] = acc;
}

// ---------------- pull aggregation (64-wide), 4-way unrolled edge loop ----------------
template <bool RELU>
__global__ void k_agg64(const int* __restrict__ rowptr, const int* __restrict__ srcs,
                        const float* __restrict__ dinv, const float* __restrict__ h,
                        const float* __restrict__ b, float* __restrict__ out) {
    int t = threadIdx.x;
    int n = blockIdx.x * 4 + (t >> 6);
    if (n >= NN) return;
    int c = t & 63;
    int e0 = rowptr[n], e1 = rowptr[n + 1];
    float dvn = dinv[n];
    float acc0 = 0.f, acc1 = 0.f, acc2 = 0.f, acc3 = 0.f;
    int j = e0;
    for (; j + 3 < e1; j += 4) {
        int s0 = srcs[j], s1 = srcs[j + 1], s2 = srcs[j + 2], s3 = srcs[j + 3];
        float w0 = dinv[s0], w1 = dinv[s1], w2 = dinv[s2], w3 = dinv[s3];
        acc0 += h[(size_t)s0 * 64 + c] * w0;
        acc1 += h[(size_t)s1 * 64 + c] * w1;
        acc2 += h[(size_t)s2 * 64 + c] * w2;
        acc3 += h[(size_t)s3 * 64 + c] * w3;
    }
    for (; j < e1; j++) {
        int s0 = srcs[j];
        acc0 += h[(size_t)s0 * 64 + c] * dinv[s0];
    }
    float v = ((acc0 + acc1) + (acc2 + acc3)) * dvn
            + h[(size_t)n * 64 + c] * dvn * dvn + b[c];
    if (RELU) v = fmaxf(v, 0.f);
    out[(size_t)n * 64 + c] = v;
}

// ---------------- layer-3 agg fused with emb-mean: wave/node, 4 edge slots ----------------
__global__ void k_agg16_reduce(const int* __restrict__ rowptr, const int* __restrict__ srcs,
                               const float* __restrict__ dinv, const float* __restrict__ h,
                               const float* __restrict__ b, float* __restrict__ red) {
    int t = threadIdx.x;
    int lane = t & 63, wv = t >> 6;
    int c = lane & 15, slot = lane >> 4;
    int gw = blockIdx.x * 4 + wv;
    int nw = gridDim.x * 4;
    float acc = 0.f;
    for (int n = gw; n < NN; n += nw) {
        int e0 = rowptr[n], e1 = rowptr[n + 1];
        float dvn = dinv[n];
        float es = 0.f;
        for (int j = e0 + slot; j < e1; j += 4) {
            int s0 = srcs[j];
            es += h[(size_t)s0 * 16 + c] * dinv[s0];
        }
        es += __shfl_xor(es, 16, 64);
        es += __shfl_xor(es, 32, 64);
        if (slot == 0)
            acc += es * dvn + h[(size_t)n * 16 + c] * dvn * dvn + b[c];
    }
    __shared__ float s[4][16];
    if (slot == 0) s[wv][c] = acc;
    __syncthreads();
    if (t < 16) atomicAdd(&red[t], (s[0][t] + s[1][t]) + (s[2][t] + s[3][t]));
}

// ---------------- global-feature reduction ----------------
__global__ void k_reduce_gf(const float* __restrict__ x, float* __restrict__ red) {
    int t = threadIdx.x;
    float sc = 0, sa = 0, so = 0, sl = 0, sm = 0;
    for (int i = blockIdx.x * 256 + t; i < NN; i += gridDim.x * 256) {
        float lam = x[i * 5 + 0], mu = x[i * 5 + 1];
        float c = x[i * 5 + 2], a = x[i * 5 + 3], o = x[i * 5 + 4];
        sc += c; sa += a; so += o; sl += lam * c; sm += mu * c;
    }
    __shared__ float s[256];
    float vals[5] = {sc, sa, so, sl, sm};
#pragma unroll
    for (int k = 0; k < 5; k++) {
        s[t] = vals[k];
        __syncthreads();
        for (int off = 128; off > 0; off >>= 1) {
            if (t < off) s[t] += s[t + off];
            __syncthreads();
        }
        if (t == 0) atomicAdd(&red[16 + k], s[0]);
        __syncthreads();
    }
}

// ---------------- final MLP (1 block, 64 threads) ----------------
__device__ __forceinline__ float softplus_f(float x) {
    return (x > 20.f) ? x : log1pf(expf(x));
}

__global__ void k_mlp(const float* __restrict__ red,
                      const float* __restrict__ T, const float* __restrict__ Tmax,
                      const float* __restrict__ P1, const float* __restrict__ pb1,
                      const float* __restrict__ P2, const float* __restrict__ pb2,
                      const float* __restrict__ P3, const float* __restrict__ pb3,
                      float* __restrict__ out) {
    __shared__ float emb[24];
    __shared__ float hm1[64];
    __shared__ float hm2[32];
    __shared__ float val[4];
    int t = threadIdx.x;
    if (t < 16) emb[t] = red[t] / (float)NN;
    if (t == 0) {
        float sc = red[16], sa = red[17], so = red[18], sl = red[19], sm = red[20];
        float Tn = T[0] / Tmax[0];
        emb[16] = sc;
        emb[17] = sa;
        emb[18] = so;
        emb[19] = sa + so;
        float safe = fmaxf(sc, 1.0f);
        bool has = sc > 0.f;
        emb[20] = has ? sl / safe : 0.f;
        emb[21] = has ? sm / safe : 0.f;
        emb[22] = Tn * 50.f;
        emb[23] = (1.f / (1.f + Tn)) * 50.f;
    }
    __syncthreads();
    {
        float acc = pb1[t];
#pragma unroll
        for (int k = 0; k < 24; k++) acc += emb[k] * P1[k * 64 + t];
        hm1[t] = fmaxf(acc, 0.f);
    }
    __syncthreads();
    if (t < 32) {
        float acc = pb2[t];
#pragma unroll
        for (int k = 0; k < 64; k++) acc += hm1[k] * P2[k * 32 + t];
        hm2[t] = fmaxf(acc, 0.f);
    }
    __syncthreads();
    if (t < 4) {
        float acc = pb3[t];
#pragma unroll
        for (int k = 0; k < 32; k++) acc += hm2[k] * P3[k * 4 + t];
        val[t] = softplus_f(acc + 2.0f);
    }
    __syncthreads();
    if (t == 0) {
        float amin = 1.f + val[0];
        float amax = amin + val[1] + 0.5f;
        float bmin = 1.f + val[2];
        float bmax = bmin + val[3] + 0.5f;
        out[0] = amin; out[1] = amax; out[2] = bmin; out[3] = bmax;
    }
    if (t >= 4 && t < 28) out[t] = emb[t - 4];
}

extern "C" void kernel_launch(void* const* d_in, const int* in_sizes, int n_in,
                              void* d_out, int out_size, void* d_ws, size_t ws_size,
                              hipStream_t stream) {
    const float* x    = (const float*)d_in[0];
    const int*   ei   = (const int*)d_in[1];
    const float* T    = (const float*)d_in[2];
    const float* Tmax = (const float*)d_in[3];
    const float* W1   = (const float*)d_in[4];
    const float* b1   = (const float*)d_in[5];
    const float* W2   = (const float*)d_in[6];
    const float* b2   = (const float*)d_in[7];
    const float* W3   = (const float*)d_in[8];
    const float* b3   = (const float*)d_in[9];
    const float* P1   = (const float*)d_in[10];
    const float* pb1  = (const float*)d_in[11];
    const float* P2   = (const float*)d_in[12];
    const float* pb2  = (const float*)d_in[13];
    const float* P3   = (const float*)d_in[14];
    const float* pb3  = (const float*)d_in[15];
    float* out = (float*)d_out;

    // workspace carve-up (cnt, cursor, red contiguous -> one memset)
    char* w = (char*)d_ws;
    float* bufH   = (float*)w;                 w += (size_t)NN * 64 * 4;
    float* bufA   = (float*)w;                 w += (size_t)NN * 64 * 4;
    int*   cnt    = (int*)w;                   w += (size_t)NN * 4;
    int*   cursor = (int*)w;                   w += (size_t)NN * 4;
    float* red    = (float*)w;                 w += 32 * 4;
    float* dinv   = (float*)w;                 w += (size_t)NN * 4;
    int*   incl   = (int*)w;                   w += (size_t)NN * 4;
    int*   rowptr = (int*)w;                   w += (size_t)(NN + 1) * 4;
    int*   srcs   = (int*)w;                   w += (size_t)NE * 4;
    int*   bsum   = (int*)w;                   w += 512 * 4;

    hipMemsetAsync(cnt, 0, (2 * (size_t)NN + 32) * sizeof(int), stream);

    // CSR build (by dst) + dinv
    k_hist<<<(NE + 255) / 256, 256, 0, stream>>>(ei, cnt);
    k_scan_block<<<NB_SCAN, 256, 0, stream>>>(cnt, incl, bsum, dinv);
    k_scan_bsum<<<1, 512, 0, stream>>>(bsum);
    k_scan_add<<<NB_SCAN, 256, 0, stream>>>(cnt, incl, bsum, rowptr);
    k_scatter<<<(NE + 255) / 256, 256, 0, stream>>>(ei, rowptr, cursor, srcs);

    // layer 1
    k_lin_first<<<(NN + 3) / 4, 256, 0, stream>>>(x, W1, bufH);
    k_agg64<true><<<(NN + 3) / 4, 256, 0, stream>>>(rowptr, srcs, dinv, bufH, b1, bufA);

    // layer 2
    k_lin64<<<(NN + 3) / 4, 256, 0, stream>>>(bufA, W2, bufH);
    k_agg64<true><<<(NN + 3) / 4, 256, 0, stream>>>(rowptr, srcs, dinv, bufH, b2, bufA);

    // layer 3 (16-wide) + fused emb-mean
    k_lin3<<<(NN + 15) / 16, 256, 0, stream>>>(bufA, W3, bufH);
    k_agg16_reduce<<<2048, 256, 0, stream>>>(rowptr, srcs, dinv, bufH, b3, red);

    // global features + MLP
    k_reduce_gf<<<1024, 256, 0, stream>>>(x, red);
    k_mlp<<<1, 64, 0, stream>>>(red, T, Tmax, P1, pb1, P2, pb2, P3, pb3, out);
}

// Round 5
// 506.464 us; speedup vs baseline: 5.2089x; 1.1149x over previous
//
#include <hip/hip_runtime.h>

#define NN 100000
#define NE 1200000
#define NB_SCAN ((NN + 255) / 256)   // 391 blocks
#define NPASS 8
#define WNODES ((NN + NPASS - 1) / NPASS)   // 12500 nodes per scatter window
#define EB 128                               // blocks per scatter pass

// ---------------- CSR build ----------------
__global__ void k_hist(const int* __restrict__ ei, int* __restrict__ cnt) {
    int i = blockIdx.x * 256 + threadIdx.x;
    if (i < NE) atomicAdd(&cnt[ei[NE + i]], 1);   // dst row
}

// scan block + dinv fused (reads cnt anyway)
__global__ void k_scan_block(const int* __restrict__ cnt, int* __restrict__ incl,
                             int* __restrict__ bsum, float* __restrict__ dinv) {
    __shared__ int s[256];
    int t = threadIdx.x;
    int i = blockIdx.x * 256 + t;
    int v = (i < NN) ? cnt[i] : 0;
    if (i < NN) dinv[i] = rsqrtf((float)v + 1.0f);
    s[t] = v;
    __syncthreads();
    for (int off = 1; off < 256; off <<= 1) {
        int add = (t >= off) ? s[t - off] : 0;
        __syncthreads();
        s[t] += add;
        __syncthreads();
    }
    if (i < NN) incl[i] = s[t];
    if (t == 255) bsum[blockIdx.x] = s[255];
}

__global__ void k_scan_bsum(int* __restrict__ bsum) {
    __shared__ int s[512];
    int t = threadIdx.x;
    s[t] = (t < NB_SCAN) ? bsum[t] : 0;
    __syncthreads();
    for (int off = 1; off < 512; off <<= 1) {
        int add = (t >= off) ? s[t - off] : 0;
        __syncthreads();
        s[t] += add;
        __syncthreads();
    }
    if (t < NB_SCAN) bsum[t] = s[t];
}

__global__ void k_scan_add(const int* __restrict__ cnt, const int* __restrict__ incl,
                           const int* __restrict__ bsum, int* __restrict__ rowptr) {
    int i = blockIdx.x * 256 + threadIdx.x;
    if (i >= NN) return;
    int base = (blockIdx.x > 0) ? bsum[blockIdx.x - 1] : 0;
    rowptr[i] = base + incl[i] - cnt[i];   // exclusive scan
    if (i == 0) rowptr[NN] = NE;
}

// windowed scatter: pass p only scatters edges whose dst is in window p.
// Pass = blockIdx-major so passes run roughly sequentially (locality heuristic
// only; atomics guarantee correctness under any interleaving).
__global__ void k_scatter_win(const int* __restrict__ ei, const int* __restrict__ rowptr,
                              int* __restrict__ cursor, int* __restrict__ srcs) {
    int pass = blockIdx.x / EB;
    int blk  = blockIdx.x % EB;
    int lo = pass * WNODES;
    int hi = lo + WNODES;   // NN not multiple-guarded: window 7 covers the tail
    for (int e = blk * 256 + threadIdx.x; e < NE; e += EB * 256) {
        int dst = ei[NE + e];
        if (dst >= lo && dst < hi) {
            int pos = rowptr[dst] + atomicAdd(&cursor[dst], 1);
            srcs[pos] = ei[e];
        }
    }
}

// ---------------- layer 1: aggregate x (5-wide) BEFORE matmul ----------------
// aggx[n] = (sum_{s in nbr(n)} x[s]*dinv[s]) * dinv[n] + x[n]*dinv[n]^2
__global__ void k_aggx(const int* __restrict__ rowptr, const int* __restrict__ srcs,
                       const float* __restrict__ dinv, const float* __restrict__ x,
                       float* __restrict__ aggx) {
    int t = threadIdx.x;
    int n = blockIdx.x * 4 + (t >> 6);
    if (n >= NN) return;
    int lane = t & 63, c = lane & 7, slot = lane >> 3;
    int e0 = rowptr[n], e1 = rowptr[n + 1];
    float es = 0.f;
    if (c < 5) {
        for (int j = e0 + slot; j < e1; j += 8) {
            int s = srcs[j];
            es += x[(size_t)s * 5 + c] * dinv[s];
        }
    }
    es += __shfl_xor(es, 8, 64);
    es += __shfl_xor(es, 16, 64);
    es += __shfl_xor(es, 32, 64);
    float dvn = dinv[n];
    if (slot == 0 && c < 5)
        aggx[(size_t)n * 5 + c] = es * dvn + x[(size_t)n * 5 + c] * dvn * dvn;
}

// (N,5) @ (5,64) + b, relu -> h1
__global__ void k_lin_first(const float* __restrict__ aggx, const float* __restrict__ W,
                            const float* __restrict__ b, float* __restrict__ h) {
    __shared__ float Ws[5 * 64];
    __shared__ float bs[64];
    int t = threadIdx.x;
    for (int i = t; i < 320; i += 256) Ws[i] = W[i];
    if (t < 64) bs[t] = b[t];
    __syncthreads();
    int r = t >> 6, c = t & 63;
    int row = blockIdx.x * 4 + r;
    if (row >= NN) return;
    float acc = bs[c];
#pragma unroll
    for (int k = 0; k < 5; k++) acc += aggx[(size_t)row * 5 + k] * Ws[k * 64 + c];
    h[(size_t)row * 64 + c] = fmaxf(acc, 0.f);
}

// ---------------- matmuls ----------------
__global__ void k_lin64(const float* __restrict__ in, const float* __restrict__ W,
                        float* __restrict__ h) {
    __shared__ float Ws[64 * 64];
    __shared__ float rows[256];
    int t = threadIdx.x;
    for (int i = t; i < 4096; i += 256) Ws[i] = W[i];
    int base = blockIdx.x * 4;
    int gidx = base * 64 + t;
    rows[t] = (gidx < NN * 64) ? in[gidx] : 0.f;
    __syncthreads();
    int r = t >> 6, c = t & 63, row = base + r;
    if (row >= NN) return;
    float acc = 0.f;
#pragma unroll
    for (int k = 0; k < 64; k++) acc += rows[r * 64 + k] * Ws[k * 64 + c];
    h[(size_t)row * 64 + c] = acc;
}

__global__ void k_lin3(const float* __restrict__ in, const float* __restrict__ W,
                       float* __restrict__ h) {
    __shared__ float Ws[64 * 16];
    __shared__ float rows[16 * 64];
    int t = threadIdx.x;
    for (int i = t; i < 1024; i += 256) Ws[i] = W[i];
    int base = blockIdx.x * 16;
    for (int i = t; i < 1024; i += 256) {
        int g = base * 64 + i;
        rows[i] = (g < NN * 64) ? in[g] : 0.f;
    }
    __syncthreads();
    int r = t >> 4, c = t & 15, row = base + r;
    if (row >= NN) return;
    float acc = 0.f;
#pragma unroll
    for (int k = 0; k < 64; k++) acc += rows[r * 64 + k] * Ws[k * 16 + c];
    h[(size_t)row * 16 + c] = acc;
}

// ---------------- pull aggregation (64-wide), 4-way unrolled edge loop ----------------
template <bool RELU>
__global__ void k_agg64(const int* __restrict__ rowptr, const int* __restrict__ srcs,
                        const float* __restrict__ dinv, const float* __restrict__ h,
                        const float* __restrict__ b, float* __restrict__ out) {
    int t = threadIdx.x;
    int n = blockIdx.x * 4 + (t >> 6);
    if (n >= NN) return;
    int c = t & 63;
    int e0 = rowptr[n], e1 = rowptr[n + 1];
    float dvn = dinv[n];
    float acc0 = 0.f, acc1 = 0.f, acc2 = 0.f, acc3 = 0.f;
    int j = e0;
    for (; j + 3 < e1; j += 4) {
        int s0 = srcs[j], s1 = srcs[j + 1], s2 = srcs[j + 2], s3 = srcs[j + 3];
        float w0 = dinv[s0], w1 = dinv[s1], w2 = dinv[s2], w3 = dinv[s3];
        acc0 += h[(size_t)s0 * 64 + c] * w0;
        acc1 += h[(size_t)s1 * 64 + c] * w1;
        acc2 += h[(size_t)s2 * 64 + c] * w2;
        acc3 += h[(size_t)s3 * 64 + c] * w3;
    }
    for (; j < e1; j++) {
        int s0 = srcs[j];
        acc0 += h[(size_t)s0 * 64 + c] * dinv[s0];
    }
    float v = ((acc0 + acc1) + (acc2 + acc3)) * dvn
            + h[(size_t)n * 64 + c] * dvn * dvn + b[c];
    if (RELU) v = fmaxf(v, 0.f);
    out[(size_t)n * 64 + c] = v;
}

// ---------------- layer-3 agg fused with emb-mean: wave/node, 4 edge slots ----------------
__global__ void k_agg16_reduce(const int* __restrict__ rowptr, const int* __restrict__ srcs,
                               const float* __restrict__ dinv, const float* __restrict__ h,
                               const float* __restrict__ b, float* __restrict__ red) {
    int t = threadIdx.x;
    int lane = t & 63, wv = t >> 6;
    int c = lane & 15, slot = lane >> 4;
    int gw = blockIdx.x * 4 + wv;
    int nw = gridDim.x * 4;
    float acc = 0.f;
    for (int n = gw; n < NN; n += nw) {
        int e0 = rowptr[n], e1 = rowptr[n + 1];
        float dvn = dinv[n];
        float es = 0.f;
        for (int j = e0 + slot; j < e1; j += 4) {
            int s0 = srcs[j];
            es += h[(size_t)s0 * 16 + c] * dinv[s0];
        }
        es += __shfl_xor(es, 16, 64);
        es += __shfl_xor(es, 32, 64);
        if (slot == 0)
            acc += es * dvn + h[(size_t)n * 16 + c] * dvn * dvn + b[c];
    }
    __shared__ float s[4][16];
    if (slot == 0) s[wv][c] = acc;
    __syncthreads();
    if (t < 16) atomicAdd(&red[t], (s[0][t] + s[1][t]) + (s[2][t] + s[3][t]));
}

// ---------------- global-feature reduction ----------------
__global__ void k_reduce_gf(const float* __restrict__ x, float* __restrict__ red) {
    int t = threadIdx.x;
    float sc = 0, sa = 0, so = 0, sl = 0, sm = 0;
    for (int i = blockIdx.x * 256 + t; i < NN; i += gridDim.x * 256) {
        float lam = x[i * 5 + 0], mu = x[i * 5 + 1];
        float c = x[i * 5 + 2], a = x[i * 5 + 3], o = x[i * 5 + 4];
        sc += c; sa += a; so += o; sl += lam * c; sm += mu * c;
    }
    __shared__ float s[256];
    float vals[5] = {sc, sa, so, sl, sm};
#pragma unroll
    for (int k = 0; k < 5; k++) {
        s[t] = vals[k];
        __syncthreads();
        for (int off = 128; off > 0; off >>= 1) {
            if (t < off) s[t] += s[t + off];
            __syncthreads();
        }
        if (t == 0) atomicAdd(&red[16 + k], s[0]);
        __syncthreads();
    }
}

// ---------------- final MLP (1 block, 64 threads) ----------------
__device__ __forceinline__ float softplus_f(float x) {
    return (x > 20.f) ? x : log1pf(expf(x));
}

__global__ void k_mlp(const float* __restrict__ red,
                      const float* __restrict__ T, const float* __restrict__ Tmax,
                      const float* __restrict__ P1, const float* __restrict__ pb1,
                      const float* __restrict__ P2, const float* __restrict__ pb2,
                      const float* __restrict__ P3, const float* __restrict__ pb3,
                      float* __restrict__ out) {
    __shared__ float emb[24];
    __shared__ float hm1[64];
    __shared__ float hm2[32];
    __shared__ float val[4];
    int t = threadIdx.x;
    if (t < 16) emb[t] = red[t] / (float)NN;
    if (t == 0) {
        float sc = red[16], sa = red[17], so = red[18], sl = red[19], sm = red[20];
        float Tn = T[0] / Tmax[0];
        emb[16] = sc;
        emb[17] = sa;
        emb[18] = so;
        emb[19] = sa + so;
        float safe = fmaxf(sc, 1.0f);
        bool has = sc > 0.f;
        emb[20] = has ? sl / safe : 0.f;
        emb[21] = has ? sm / safe : 0.f;
        emb[22] = Tn * 50.f;
        emb[23] = (1.f / (1.f + Tn)) * 50.f;
    }
    __syncthreads();
    {
        float acc = pb1[t];
#pragma unroll
        for (int k = 0; k < 24; k++) acc += emb[k] * P1[k * 64 + t];
        hm1[t] = fmaxf(acc, 0.f);
    }
    __syncthreads();
    if (t < 32) {
        float acc = pb2[t];
#pragma unroll
        for (int k = 0; k < 64; k++) acc += hm1[k] * P2[k * 32 + t];
        hm2[t] = fmaxf(acc, 0.f);
    }
    __syncthreads();
    if (t < 4) {
        float acc = pb3[t];
#pragma unroll
        for (int k = 0; k < 32; k++) acc += hm2[k] * P3[k * 4 + t];
        val[t] = softplus_f(acc + 2.0f);
    }
    __syncthreads();
    if (t == 0) {
        float amin = 1.f + val[0];
        float amax = amin + val[1] + 0.5f;
        float bmin = 1.f + val[2];
        float bmax = bmin + val[3] + 0.5f;
        out[0] = amin; out[1] = amax; out[2] = bmin; out[3] = bmax;
    }
    if (t >= 4 && t < 28) out[t] = emb[t - 4];
}

extern "C" void kernel_launch(void* const* d_in, const int* in_sizes, int n_in,
                              void* d_out, int out_size, void* d_ws, size_t ws_size,
                              hipStream_t stream) {
    const float* x    = (const float*)d_in[0];
    const int*   ei   = (const int*)d_in[1];
    const float* T    = (const float*)d_in[2];
    const float* Tmax = (const float*)d_in[3];
    const float* W1   = (const float*)d_in[4];
    const float* b1   = (const float*)d_in[5];
    const float* W2   = (const float*)d_in[6];
    const float* b2   = (const float*)d_in[7];
    const float* W3   = (const float*)d_in[8];
    const float* b3   = (const float*)d_in[9];
    const float* P1   = (const float*)d_in[10];
    const float* pb1  = (const float*)d_in[11];
    const float* P2   = (const float*)d_in[12];
    const float* pb2  = (const float*)d_in[13];
    const float* P3   = (const float*)d_in[14];
    const float* pb3  = (const float*)d_in[15];
    float* out = (float*)d_out;

    // workspace carve-up (cnt, cursor, red contiguous -> one memset)
    char* w = (char*)d_ws;
    float* bufH   = (float*)w;                 w += (size_t)NN * 64 * 4;
    float* bufA   = (float*)w;                 w += (size_t)NN * 64 * 4;
    int*   cnt    = (int*)w;                   w += (size_t)NN * 4;
    int*   cursor = (int*)w;                   w += (size_t)NN * 4;
    float* red    = (float*)w;                 w += 32 * 4;
    float* dinv   = (float*)w;                 w += (size_t)NN * 4;
    int*   incl   = (int*)w;                   w += (size_t)NN * 4;
    int*   rowptr = (int*)w;                   w += (size_t)(NN + 1) * 4;
    int*   srcs   = (int*)w;                   w += (size_t)NE * 4;
    int*   bsum   = (int*)w;                   w += 512 * 4;
    float* aggx   = (float*)w;                 w += (size_t)NN * 5 * 4;

    hipMemsetAsync(cnt, 0, (2 * (size_t)NN + 32) * sizeof(int), stream);

    // CSR build (by dst) + dinv
    k_hist<<<(NE + 255) / 256, 256, 0, stream>>>(ei, cnt);
    k_scan_block<<<NB_SCAN, 256, 0, stream>>>(cnt, incl, bsum, dinv);
    k_scan_bsum<<<1, 512, 0, stream>>>(bsum);
    k_scan_add<<<NB_SCAN, 256, 0, stream>>>(cnt, incl, bsum, rowptr);
    k_scatter_win<<<NPASS * EB, 256, 0, stream>>>(ei, rowptr, cursor, srcs);

    // layer 1 (commuted: aggregate 5-wide x first, then matmul+bias+relu)
    k_aggx<<<(NN + 3) / 4, 256, 0, stream>>>(rowptr, srcs, dinv, x, aggx);
    k_lin_first<<<(NN + 3) / 4, 256, 0, stream>>>(aggx, W1, b1, bufA);

    // layer 2
    k_lin64<<<(NN + 3) / 4, 256, 0, stream>>>(bufA, W2, bufH);
    k_agg64<true><<<(NN + 3) / 4, 256, 0, stream>>>(rowptr, srcs, dinv, bufH, b2, bufA);

    // layer 3 (16-wide) + fused emb-mean
    k_lin3<<<(NN + 15) / 16, 256, 0, stream>>>(bufA, W3, bufH);
    k_agg16_reduce<<<2048, 256, 0, stream>>>(rowptr, srcs, dinv, bufH, b3, red);

    // global features + MLP
    k_reduce_gf<<<1024, 256, 0, stream>>>(x, red);
    k_mlp<<<1, 64, 0, stream>>>(red, T, Tmax, P1, pb1, P2, pb2, P3, pb3, out);
}

// Round 6
// 470.415 us; speedup vs baseline: 5.6081x; 1.0766x over previous
//
#include <hip/hip_runtime.h>

#define NN 100000
#define NE 1200000
#define NB_SCAN ((NN + 255) / 256)   // 391 blocks
#define NPASS 8
#define WNODES ((NN + NPASS - 1) / NPASS)   // 12500 nodes per scatter window
#define EB 128                               // blocks per scatter pass
#define GF_BLOCKS 64
#define P16_BLOCKS 1024

// ---------------- CSR build ----------------
__global__ void k_hist(const int* __restrict__ ei, int* __restrict__ cnt) {
    int i = blockIdx.x * 256 + threadIdx.x;
    if (i < NE) atomicAdd(&cnt[ei[NE + i]], 1);   // dst row
}

// scan block + dinv fused (reads cnt anyway)
__global__ void k_scan_block(const int* __restrict__ cnt, int* __restrict__ incl,
                             int* __restrict__ bsum, float* __restrict__ dinv) {
    __shared__ int s[256];
    int t = threadIdx.x;
    int i = blockIdx.x * 256 + t;
    int v = (i < NN) ? cnt[i] : 0;
    if (i < NN) dinv[i] = rsqrtf((float)v + 1.0f);
    s[t] = v;
    __syncthreads();
    for (int off = 1; off < 256; off <<= 1) {
        int add = (t >= off) ? s[t - off] : 0;
        __syncthreads();
        s[t] += add;
        __syncthreads();
    }
    if (i < NN) incl[i] = s[t];
    if (t == 255) bsum[blockIdx.x] = s[255];
}

__global__ void k_scan_bsum(int* __restrict__ bsum) {
    __shared__ int s[512];
    int t = threadIdx.x;
    s[t] = (t < NB_SCAN) ? bsum[t] : 0;
    __syncthreads();
    for (int off = 1; off < 512; off <<= 1) {
        int add = (t >= off) ? s[t - off] : 0;
        __syncthreads();
        s[t] += add;
        __syncthreads();
    }
    if (t < NB_SCAN) bsum[t] = s[t];
}

__global__ void k_scan_add(const int* __restrict__ cnt, const int* __restrict__ incl,
                           const int* __restrict__ bsum, int* __restrict__ rowptr) {
    int i = blockIdx.x * 256 + threadIdx.x;
    if (i >= NN) return;
    int base = (blockIdx.x > 0) ? bsum[blockIdx.x - 1] : 0;
    rowptr[i] = base + incl[i] - cnt[i];   // exclusive scan
    if (i == 0) rowptr[NN] = NE;
}

// XCD-affine windowed scatter: window = blockIdx % 8 so (round-robin
// dispatch heuristic) all blocks of a window run on one XCD -> window's
// srcs lines live in that XCD's L2. Locality heuristic only; atomics
// guarantee correctness under any block->XCD mapping.
__global__ void k_scatter_win(const int* __restrict__ ei, const int* __restrict__ rowptr,
                              int* __restrict__ cursor, int* __restrict__ srcs) {
    int pass = blockIdx.x & (NPASS - 1);
    int blk  = blockIdx.x / NPASS;
    int lo = pass * WNODES;
    int hi = lo + WNODES;   // window 7 covers the tail (NN < 8*12500)
    for (int e = blk * 256 + threadIdx.x; e < NE; e += EB * 256) {
        int dst = ei[NE + e];
        if (dst >= lo && dst < hi) {
            int pos = rowptr[dst] + atomicAdd(&cursor[dst], 1);
            srcs[pos] = ei[e];
        }
    }
}

// ---------------- layer 1: aggregate x (5-wide) BEFORE matmul ----------------
__global__ void k_aggx(const int* __restrict__ rowptr, const int* __restrict__ srcs,
                       const float* __restrict__ dinv, const float* __restrict__ x,
                       float* __restrict__ aggx) {
    int t = threadIdx.x;
    int n = blockIdx.x * 4 + (t >> 6);
    if (n >= NN) return;
    int lane = t & 63, c = lane & 7, slot = lane >> 3;
    int e0 = rowptr[n], e1 = rowptr[n + 1];
    float es = 0.f;
    if (c < 5) {
        for (int j = e0 + slot; j < e1; j += 8) {
            int s = srcs[j];
            es += x[(size_t)s * 5 + c] * dinv[s];
        }
    }
    es += __shfl_xor(es, 8, 64);
    es += __shfl_xor(es, 16, 64);
    es += __shfl_xor(es, 32, 64);
    float dvn = dinv[n];
    if (slot == 0 && c < 5)
        aggx[(size_t)n * 5 + c] = es * dvn + x[(size_t)n * 5 + c] * dvn * dvn;
}

// (N,5) @ (5,64) + b, relu -> h1
__global__ void k_lin_first(const float* __restrict__ aggx, const float* __restrict__ W,
                            const float* __restrict__ b, float* __restrict__ h) {
    __shared__ float Ws[5 * 64];
    __shared__ float bs[64];
    int t = threadIdx.x;
    for (int i = t; i < 320; i += 256) Ws[i] = W[i];
    if (t < 64) bs[t] = b[t];
    __syncthreads();
    int r = t >> 6, c = t & 63;
    int row = blockIdx.x * 4 + r;
    if (row >= NN) return;
    float acc = bs[c];
#pragma unroll
    for (int k = 0; k < 5; k++) acc += aggx[(size_t)row * 5 + k] * Ws[k * 64 + c];
    h[(size_t)row * 64 + c] = fmaxf(acc, 0.f);
}

// ---------------- matmuls ----------------
__global__ void k_lin64(const float* __restrict__ in, const float* __restrict__ W,
                        float* __restrict__ h) {
    __shared__ float Ws[64 * 64];
    __shared__ float rows[256];
    int t = threadIdx.x;
    for (int i = t; i < 4096; i += 256) Ws[i] = W[i];
    int base = blockIdx.x * 4;
    int gidx = base * 64 + t;
    rows[t] = (gidx < NN * 64) ? in[gidx] : 0.f;
    __syncthreads();
    int r = t >> 6, c = t & 63, row = base + r;
    if (row >= NN) return;
    float acc = 0.f;
#pragma unroll
    for (int k = 0; k < 64; k++) acc += rows[r * 64 + k] * Ws[k * 64 + c];
    h[(size_t)row * 64 + c] = acc;
}

__global__ void k_lin3(const float* __restrict__ in, const float* __restrict__ W,
                       float* __restrict__ h) {
    __shared__ float Ws[64 * 16];
    __shared__ float rows[16 * 64];
    int t = threadIdx.x;
    for (int i = t; i < 1024; i += 256) Ws[i] = W[i];
    int base = blockIdx.x * 16;
    for (int i = t; i < 1024; i += 256) {
        int g = base * 64 + i;
        rows[i] = (g < NN * 64) ? in[g] : 0.f;
    }
    __syncthreads();
    int r = t >> 4, c = t & 15, row = base + r;
    if (row >= NN) return;
    float acc = 0.f;
#pragma unroll
    for (int k = 0; k < 64; k++) acc += rows[r * 64 + k] * Ws[k * 16 + c];
    h[(size_t)row * 16 + c] = acc;
}

// ---------------- pull aggregation (64-wide), 4-way unrolled edge loop ----------------
template <bool RELU>
__global__ void k_agg64(const int* __restrict__ rowptr, const int* __restrict__ srcs,
                        const float* __restrict__ dinv, const float* __restrict__ h,
                        const float* __restrict__ b, float* __restrict__ out) {
    int t = threadIdx.x;
    int n = blockIdx.x * 4 + (t >> 6);
    if (n >= NN) return;
    int c = t & 63;
    int e0 = rowptr[n], e1 = rowptr[n + 1];
    float dvn = dinv[n];
    float acc0 = 0.f, acc1 = 0.f, acc2 = 0.f, acc3 = 0.f;
    int j = e0;
    for (; j + 3 < e1; j += 4) {
        int s0 = srcs[j], s1 = srcs[j + 1], s2 = srcs[j + 2], s3 = srcs[j + 3];
        float w0 = dinv[s0], w1 = dinv[s1], w2 = dinv[s2], w3 = dinv[s3];
        acc0 += h[(size_t)s0 * 64 + c] * w0;
        acc1 += h[(size_t)s1 * 64 + c] * w1;
        acc2 += h[(size_t)s2 * 64 + c] * w2;
        acc3 += h[(size_t)s3 * 64 + c] * w3;
    }
    for (; j < e1; j++) {
        int s0 = srcs[j];
        acc0 += h[(size_t)s0 * 64 + c] * dinv[s0];
    }
    float v = ((acc0 + acc1) + (acc2 + acc3)) * dvn
            + h[(size_t)n * 64 + c] * dvn * dvn + b[c];
    if (RELU) v = fmaxf(v, 0.f);
    out[(size_t)n * 64 + c] = v;
}

// ---------------- layer-3 agg + emb partials (NO global atomics) ----------------
__global__ void k_agg16_part(const int* __restrict__ rowptr, const int* __restrict__ srcs,
                             const float* __restrict__ dinv, const float* __restrict__ h,
                             const float* __restrict__ b, float* __restrict__ part16) {
    int t = threadIdx.x;
    int lane = t & 63, wv = t >> 6;
    int c = lane & 15, slot = lane >> 4;
    int gw = blockIdx.x * 4 + wv;
    int nw = gridDim.x * 4;
    float acc = 0.f;
    for (int n = gw; n < NN; n += nw) {
        int e0 = rowptr[n], e1 = rowptr[n + 1];
        float dvn = dinv[n];
        float es = 0.f;
        for (int j = e0 + slot; j < e1; j += 4) {
            int s0 = srcs[j];
            es += h[(size_t)s0 * 16 + c] * dinv[s0];
        }
        es += __shfl_xor(es, 16, 64);
        es += __shfl_xor(es, 32, 64);
        if (slot == 0)
            acc += es * dvn + h[(size_t)n * 16 + c] * dvn * dvn + b[c];
    }
    __shared__ float s[4][16];
    if (slot == 0) s[wv][c] = acc;
    __syncthreads();
    if (t < 16) part16[blockIdx.x * 16 + t] = (s[0][t] + s[1][t]) + (s[2][t] + s[3][t]);
}

// ---------------- global-feature partials (NO global atomics) ----------------
__global__ void k_gf_part(const float* __restrict__ x, float* __restrict__ gfpart) {
    int t = threadIdx.x;
    float sc = 0, sa = 0, so = 0, sl = 0, sm = 0;
    for (int i = blockIdx.x * 256 + t; i < NN; i += gridDim.x * 256) {
        float lam = x[i * 5 + 0], mu = x[i * 5 + 1];
        float c = x[i * 5 + 2], a = x[i * 5 + 3], o = x[i * 5 + 4];
        sc += c; sa += a; so += o; sl += lam * c; sm += mu * c;
    }
    __shared__ float s[256];
    float vals[5] = {sc, sa, so, sl, sm};
#pragma unroll
    for (int k = 0; k < 5; k++) {
        s[t] = vals[k];
        __syncthreads();
        for (int off = 128; off > 0; off >>= 1) {
            if (t < off) s[t] += s[t + off];
            __syncthreads();
        }
        if (t == 0) gfpart[blockIdx.x * 5 + k] = s[0];
        __syncthreads();
    }
}

// ---------------- final reduce + MLP (1 block, 256 threads) ----------------
__device__ __forceinline__ float softplus_f(float x) {
    return (x > 20.f) ? x : log1pf(expf(x));
}

__global__ void k_mlp(const float* __restrict__ part16, const float* __restrict__ gfpart,
                      const float* __restrict__ T, const float* __restrict__ Tmax,
                      const float* __restrict__ P1, const float* __restrict__ pb1,
                      const float* __restrict__ P2, const float* __restrict__ pb2,
                      const float* __restrict__ P3, const float* __restrict__ pb3,
                      float* __restrict__ out) {
    __shared__ float s[256];
    __shared__ float emb[24];
    __shared__ float hm1[64];
    __shared__ float hm2[32];
    __shared__ float val[4];
    int t = threadIdx.x;
    // reduce part16 (P16_BLOCKS x 16): c = t&15, group g = t>>4 sums strided rows
    {
        int c = t & 15, g = t >> 4;
        float acc = 0.f;
        for (int r = g; r < P16_BLOCKS; r += 16) acc += part16[r * 16 + c];
        s[t] = acc;
        __syncthreads();
        for (int off = 128; off >= 16; off >>= 1) {
            if (t < off) s[t] += s[t + off];
            __syncthreads();
        }
        if (t < 16) emb[t] = s[t] / (float)NN;
    }
    // reduce gfpart (GF_BLOCKS x 5)
    if (t < 5) {
        float acc = 0.f;
        for (int r = 0; r < GF_BLOCKS; r++) acc += gfpart[r * 5 + t];
        s[t] = acc;   // reuse s[0..4] after barrier below
    }
    __syncthreads();
    if (t == 0) {
        float sc = s[0], sa = s[1], so = s[2], sl = s[3], sm = s[4];
        float Tn = T[0] / Tmax[0];
        emb[16] = sc;
        emb[17] = sa;
        emb[18] = so;
        emb[19] = sa + so;
        float safe = fmaxf(sc, 1.0f);
        bool has = sc > 0.f;
        emb[20] = has ? sl / safe : 0.f;
        emb[21] = has ? sm / safe : 0.f;
        emb[22] = Tn * 50.f;
        emb[23] = (1.f / (1.f + Tn)) * 50.f;
    }
    __syncthreads();
    if (t < 64) {
        float acc = pb1[t];
#pragma unroll
        for (int k = 0; k < 24; k++) acc += emb[k] * P1[k * 64 + t];
        hm1[t] = fmaxf(acc, 0.f);
    }
    __syncthreads();
    if (t < 32) {
        float acc = pb2[t];
#pragma unroll
        for (int k = 0; k < 64; k++) acc += hm1[k] * P2[k * 32 + t];
        hm2[t] = fmaxf(acc, 0.f);
    }
    __syncthreads();
    if (t < 4) {
        float acc = pb3[t];
#pragma unroll
        for (int k = 0; k < 32; k++) acc += hm2[k] * P3[k * 4 + t];
        val[t] = softplus_f(acc + 2.0f);
    }
    __syncthreads();
    if (t == 0) {
        float amin = 1.f + val[0];
        float amax = amin + val[1] + 0.5f;
        float bmin = 1.f + val[2];
        float bmax = bmin + val[3] + 0.5f;
        out[0] = amin; out[1] = amax; out[2] = bmin; out[3] = bmax;
    }
    if (t >= 4 && t < 28) out[t] = emb[t - 4];
}

extern "C" void kernel_launch(void* const* d_in, const int* in_sizes, int n_in,
                              void* d_out, int out_size, void* d_ws, size_t ws_size,
                              hipStream_t stream) {
    const float* x    = (const float*)d_in[0];
    const int*   ei   = (const int*)d_in[1];
    const float* T    = (const float*)d_in[2];
    const float* Tmax = (const float*)d_in[3];
    const float* W1   = (const float*)d_in[4];
    const float* b1   = (const float*)d_in[5];
    const float* W2   = (const float*)d_in[6];
    const float* b2   = (const float*)d_in[7];
    const float* W3   = (const float*)d_in[8];
    const float* b3   = (const float*)d_in[9];
    const float* P1   = (const float*)d_in[10];
    const float* pb1  = (const float*)d_in[11];
    const float* P2   = (const float*)d_in[12];
    const float* pb2  = (const float*)d_in[13];
    const float* P3   = (const float*)d_in[14];
    const float* pb3  = (const float*)d_in[15];
    float* out = (float*)d_out;

    // workspace carve-up (cnt, cursor contiguous -> one memset)
    char* w = (char*)d_ws;
    float* bufH   = (float*)w;                 w += (size_t)NN * 64 * 4;
    float* bufA   = (float*)w;                 w += (size_t)NN * 64 * 4;
    int*   cnt    = (int*)w;                   w += (size_t)NN * 4;
    int*   cursor = (int*)w;                   w += (size_t)NN * 4;
    float* dinv   = (float*)w;                 w += (size_t)NN * 4;
    int*   incl   = (int*)w;                   w += (size_t)NN * 4;
    int*   rowptr = (int*)w;                   w += (size_t)(NN + 1) * 4;
    int*   srcs   = (int*)w;                   w += (size_t)NE * 4;
    int*   bsum   = (int*)w;                   w += 512 * 4;
    float* aggx   = (float*)w;                 w += (size_t)NN * 5 * 4;
    float* part16 = (float*)w;                 w += (size_t)P16_BLOCKS * 16 * 4;
    float* gfpart = (float*)w;                 w += (size_t)GF_BLOCKS * 5 * 4;

    hipMemsetAsync(cnt, 0, 2 * (size_t)NN * sizeof(int), stream);

    // CSR build (by dst) + dinv
    k_hist<<<(NE + 255) / 256, 256, 0, stream>>>(ei, cnt);
    k_scan_block<<<NB_SCAN, 256, 0, stream>>>(cnt, incl, bsum, dinv);
    k_scan_bsum<<<1, 512, 0, stream>>>(bsum);
    k_scan_add<<<NB_SCAN, 256, 0, stream>>>(cnt, incl, bsum, rowptr);
    k_scatter_win<<<NPASS * EB, 256, 0, stream>>>(ei, rowptr, cursor, srcs);

    // layer 1 (commuted: aggregate 5-wide x first, then matmul+bias+relu)
    k_aggx<<<(NN + 3) / 4, 256, 0, stream>>>(rowptr, srcs, dinv, x, aggx);
    k_lin_first<<<(NN + 3) / 4, 256, 0, stream>>>(aggx, W1, b1, bufA);

    // layer 2
    k_lin64<<<(NN + 3) / 4, 256, 0, stream>>>(bufA, W2, bufH);
    k_agg64<true><<<(NN + 3) / 4, 256, 0, stream>>>(rowptr, srcs, dinv, bufH, b2, bufA);

    // layer 3 (16-wide) + emb partials
    k_lin3<<<(NN + 15) / 16, 256, 0, stream>>>(bufA, W3, bufH);
    k_agg16_part<<<P16_BLOCKS, 256, 0, stream>>>(rowptr, srcs, dinv, bufH, b3, part16);

    // global features + final reduce/MLP
    k_gf_part<<<GF_BLOCKS, 256, 0, stream>>>(x, gfpart);
    k_mlp<<<1, 256, 0, stream>>>(part16, gfpart, T, Tmax, P1, pb1, P2, pb2, P3, pb3, out);
}